// Round 4
// baseline (229.634 us; speedup 1.0000x reference)
//
#include <hip/hip_runtime.h>
#if __has_include(<hip/hip_bf16.h>)
#include <hip/hip_bf16.h>
#define HAVE_BF16_H 1
#endif

// Problem constants (fixed by harness)
#define NPG 96                  // nodes per graph
#define BGR 64                  // graphs
#define HID 64
#define INF 32
#define EF  16
#define DEG 8
#define NN  (BGR*NPG)           // 6144 nodes
#define NE  (BGR*NPG*DEG)       // 49152 edges
#define EPG (NPG*DEG)           // 768 edges per graph
#define PPG (NPG*NPG)           // 9216 pairs per graph
#define ROWS 24                 // rows per block (4 blocks/graph)
#define SBST 68                 // sB row stride (floats); 68*4=272 keeps 16B align
#define W2ST 72                 // sW2t row stride (ushorts); 72*2=144 keeps 16B align

typedef short bf16x8 __attribute__((ext_vector_type(8)));
typedef float f32x4  __attribute__((ext_vector_type(4)));

__device__ __forceinline__ unsigned rne2(float lo, float hi) {
    union { float f; unsigned u; } a, b; a.f = lo; b.f = hi;
    unsigned ua = a.u + 0x7FFF + ((a.u >> 16) & 1);
    unsigned ub = b.u + 0x7FFF + ((b.u >> 16) & 1);
    return (ua >> 16) | (ub & 0xFFFF0000u);
}
__device__ __forceinline__ unsigned short rne1(float x) {
    union { float f; unsigned u; } a; a.f = x;
    return (unsigned short)((a.u + 0x7FFF + ((a.u >> 16) & 1)) >> 16);
}
// Pack 2 floats -> 2 bf16 (RNE); lowers to v_cvt_pk_bf16_f32 on gfx950.
__device__ __forceinline__ unsigned cvt2(float lo, float hi) {
#ifdef HAVE_BF16_H
    __hip_bfloat162 h2 = __float22bfloat162_rn(make_float2(lo, hi));
    unsigned u; __builtin_memcpy(&u, &h2, 4); return u;
#else
    return rne2(lo, hi);
#endif
}

// ---------------------------------------------------------------------------
// Fully fused kernel: 256 blocks (one per CU), 512 threads (8 waves).
// Block (g, r0): everything for rows [r0, r0+24) of graph g's 96x96 pair
// matrix: node encode -> weight folds -> range-filtered edge dedup ->
// dense MFMA pair MLP (bitmap-predicated) -> edge-pair fix MLP.
// Only global intermediate: per-block fsea slice (L2-hot, intra-block).
//
// LDS map (61,476 B total; 2 blocks/CU capacity, grid uses 1):
//   [    0, 26112) sB    float[96][68]
//   [26112, 32256) sA    float[24][64]
//   [32256, 41472) sW2t  ushort[64][72]
//   [41472, 45568) sWEc  float[16][64]
//   [45568, 45824) sbc   float[64]
//   [45824, 61476) region reused in time:
//     phase A:  sENh float[48][64]            [45824, 58112)
//     phase F:  sU float[16][64] + sbe[64]    [45824, 50176)
//     phase B+: head2 int[2304]               [45824, 55040)
//               nxt   int[768]                [55040, 58112)
//               fkeyL int[768] (key|cnt<<16)  [58112, 61184)
//               bm24  uint[72]                [61184, 61472)
//               lcnt  int                     [61472, 61476)
// ---------------------------------------------------------------------------
__global__ __launch_bounds__(512) void fused_kernel(
    const float* __restrict__ x,
    const float* __restrict__ W_atom, const float* __restrict__ b_atom,
    const float* __restrict__ W_node, const float* __restrict__ b_node,
    const float* __restrict__ W1,     const float* __restrict__ b1,
    const float* __restrict__ ea,     const int* __restrict__ eidx,
    const float* __restrict__ W_bond, const float* __restrict__ b_bond,
    const float* __restrict__ W_edge, const float* __restrict__ b_edge,
    const float* __restrict__ W2,     const float* __restrict__ b2,
    const float* __restrict__ W3,     const float* __restrict__ b3,
    float* __restrict__ fseaG,
    float* __restrict__ out)
{
    __shared__ __align__(16) char smem[61504];
    float*          sB    = (float*)smem;
    float*          sA    = (float*)(smem + 26112);
    unsigned short* sW2t  = (unsigned short*)(smem + 32256);
    float*          sWEc  = (float*)(smem + 41472);
    float*          sbc   = (float*)(smem + 45568);
    float*          sENh  = (float*)(smem + 45824);
    float*          sU    = (float*)(smem + 45824);
    float*          sbe   = (float*)(smem + 49920);
    int*            head2 = (int*)(smem + 45824);
    int*            nxt   = (int*)(smem + 55040);
    int*            fkeyL = (int*)(smem + 58112);
    unsigned*       bm24  = (unsigned*)(smem + 61184);
    int*            lcnt  = (int*)(smem + 61472);

    const int t = threadIdx.x;
    const int wave = t >> 6, lane = t & 63;
    const int col = lane & 15, q = lane >> 4;
    const int g  = blockIdx.x >> 2;
    const int r0 = (blockIdx.x & 3) * ROWS;
    const float b3v = b3[0];

    // ===== Phase A: node chain -> sB[96], sA[24], in two 48-node halves =====
    for (int half = 0; half < 2; ++half) {
        const int nb = half * 48;
        // en for nodes nb..nb+47 (6 per wave, wave-private LDS rows)
        for (int rep = 0; rep < 6; ++rep) {
            const int nl = wave*6 + rep;            // 0..47
            const float* xr = x + (size_t)(g*NPG + nb + nl) * INF;
            float xh = b_atom[lane];
            #pragma unroll
            for (int k = 0; k < INF; ++k) xh += xr[k] * W_atom[k*HID + lane];
            sENh[nl*64 + lane] = xh;
            float en = b_node[lane];
            #pragma unroll
            for (int k = 0; k < HID; ++k) en += sENh[nl*64 + k] * W_node[k*HID + lane];
            sENh[nl*64 + lane] = en;
        }
        __syncthreads();
        // B rows nb..nb+47
        for (int rep = 0; rep < 6; ++rep) {
            const int rl = wave*6 + rep;
            float bb = 0.f;
            #pragma unroll
            for (int k = 0; k < HID; ++k) bb += sENh[rl*64 + k] * W1[(HID + k)*HID + lane];
            sB[(nb + rl)*SBST + lane] = bb;
        }
        // A rows (only the half containing r0..r0+23)
        if (r0 >= nb && r0 < nb + 48) {
            #pragma unroll
            for (int rep = 0; rep < 3; ++rep) {
                const int i = wave*3 + rep;          // 0..23
                const int rl = (r0 - nb) + i;
                float a = b1[lane];
                #pragma unroll
                for (int k = 0; k < HID; ++k) a += sENh[rl*64 + k] * W1[k*HID + lane];
                sA[i*64 + lane] = a;
            }
        }
        __syncthreads();   // sENh dead before next half / fold reuse
    }

    // W2^T -> bf16 (padded); disjoint LDS, consumed after later barriers
    for (int idx = t; idx < 4096; idx += 512)
        sW2t[(idx & 63)*W2ST + (idx >> 6)] = rne1(W2[idx]);
    { const int n = t >> 3, kk = 64 + (t & 7); sW2t[n*W2ST + kk] = 0; }

    // ===== Phase F: fold WEc = W_bond@W_edge@W1c, biasc =====
    #pragma unroll
    for (int ii2 = 0; ii2 < 2; ++ii2) {
        const int idx = t + ii2*512;                 // 0..1023
        const int r = idx >> 6, c = idx & 63;
        float s = 0.f;
        for (int k = 0; k < 64; ++k) s += W_bond[r*64 + k] * W_edge[k*64 + c];
        sU[idx] = s;
    }
    if (t < 64) {
        float s2 = b_edge[t];
        for (int k = 0; k < 64; ++k) s2 += b_bond[k] * W_edge[k*64 + t];
        sbe[t] = s2;
    }
    __syncthreads();
    #pragma unroll
    for (int ii2 = 0; ii2 < 2; ++ii2) {
        const int idx = t + ii2*512;
        const int r = idx >> 6, c = idx & 63;
        float s = 0.f;
        for (int k = 0; k < 64; ++k) s += sU[r*64 + k] * W1[(128 + k)*64 + c];
        sWEc[idx] = s;
    }
    if (t < 64) {
        float sc = 0.f;
        for (int k = 0; k < 64; ++k) sc += sbe[k] * W1[(128 + k)*64 + t];
        sbc[t] = sc;
    }
    __syncthreads();   // sU/sbe dead; dedup region can be initialized

    // ===== Phase B: range-filtered dedup (u in [r0, r0+24)) =====
    for (int idx = t; idx < ROWS*NPG; idx += 512) head2[idx] = -1;
    if (t < 72) bm24[t] = 0u;
    if (t == 0) *lcnt = 0;

    int eu[2], ev[2]; bool ein[2];
    #pragma unroll
    for (int c2 = 0; c2 < 2; ++c2) {
        const int e = t + c2*512;
        ein[c2] = false; eu[c2] = 0; ev[c2] = 0;
        if (e < EPG) {
            eu[c2] = eidx[g*EPG + e]      - g*NPG;
            ev[c2] = eidx[NE + g*EPG + e] - g*NPG;
            ein[c2] = (eu[c2] >= r0) && (eu[c2] < r0 + ROWS);
        }
    }
    __syncthreads();

    #pragma unroll
    for (int c2 = 0; c2 < 2; ++c2) {
        if (ein[c2]) {
            const int e = t + c2*512;
            const int key2 = (eu[c2] - r0)*NPG + ev[c2];
            nxt[e] = atomicExch(&head2[key2], e);
        }
    }
    __syncthreads();

    {
        const float* eag = ea + (size_t)g * EPG * EF;
        #pragma unroll
        for (int c2 = 0; c2 < 2; ++c2) {
            if (ein[c2]) {
                const int e0 = t + c2*512;
                const int key2 = (eu[c2] - r0)*NPG + ev[c2];
                if (head2[key2] == e0) {
                    float s[EF];
                    #pragma unroll
                    for (int qq = 0; qq < EF; ++qq) s[qq] = 0.f;
                    int cnt = 0;
                    for (int e = e0; e != -1; e = nxt[e]) {
                        ++cnt;
                        const float4* p = (const float4*)(eag + e*EF);
                        #pragma unroll
                        for (int q4 = 0; q4 < 4; ++q4) {
                            const float4 f = p[q4];
                            s[q4*4+0] += f.x; s[q4*4+1] += f.y;
                            s[q4*4+2] += f.z; s[q4*4+3] += f.w;
                        }
                    }
                    atomicOr(&bm24[key2 >> 5], 1u << (key2 & 31));
                    const int pos = atomicAdd(lcnt, 1);
                    fkeyL[pos] = (eu[c2]*NPG + ev[c2]) | (cnt << 16);
                    float* fp = fseaG + ((size_t)blockIdx.x * EPG + pos) * EF;
                    #pragma unroll
                    for (int qq = 0; qq < EF; ++qq) fp[qq] = s[qq];
                }
            }
        }
    }
    __syncthreads();   // fkeyL/bm24/lcnt + global fsea visible to block

    // ===== shared fragments for both MFMA phases =====
    bf16x8 w2f[4][2];
    #pragma unroll
    for (int nt = 0; nt < 4; ++nt)
        #pragma unroll
        for (int c = 0; c < 2; ++c)
            w2f[nt][c] = *(const bf16x8*)(sW2t + (nt*16 + col)*W2ST + c*32 + q*8);

    float w3l[4], b2l[4];
    #pragma unroll
    for (int nt = 0; nt < 4; ++nt) {
        w3l[nt] = W3[nt*16 + col];
        b2l[nt] = b2[nt*16 + col];
    }

    // ===== Phase C: dense pair MLP, rows r0..r0+23 x cols 0..95 =====
    #pragma unroll
    for (int rep = 0; rep < 3; ++rep) {
        const int il = wave*3 + rep;                // 0..23
        float areg[16];
        {
            const float4* Ar = (const float4*)(sA + il*64 + q*8);
            const float4 a0 = Ar[0], a1 = Ar[1];
            const float4 a2 = Ar[8], a3 = Ar[9];
            areg[0]=a0.x; areg[1]=a0.y; areg[2]=a0.z; areg[3]=a0.w;
            areg[4]=a1.x; areg[5]=a1.y; areg[6]=a1.z; areg[7]=a1.w;
            areg[8]=a2.x; areg[9]=a2.y; areg[10]=a2.z; areg[11]=a2.w;
            areg[12]=a3.x; areg[13]=a3.y; areg[14]=a3.z; areg[15]=a3.w;
        }
        float* outr = out + g*PPG + (r0 + il)*NPG;

        for (int jc = 0; jc < 6; ++jc) {
            const int j0 = jc * 16;
            union { bf16x8 v; unsigned u[4]; } h1[2];
            const float* Brow = sB + (j0 + col)*SBST + q*8;
            #pragma unroll
            for (int c = 0; c < 2; ++c) {
                const float4 b0  = *(const float4*)(Brow + c*32);
                const float4 b1v = *(const float4*)(Brow + c*32 + 4);
                float h[8];
                h[0] = fmaxf(areg[c*8+0] + b0.x, 0.f);
                h[1] = fmaxf(areg[c*8+1] + b0.y, 0.f);
                h[2] = fmaxf(areg[c*8+2] + b0.z, 0.f);
                h[3] = fmaxf(areg[c*8+3] + b0.w, 0.f);
                h[4] = fmaxf(areg[c*8+4] + b1v.x, 0.f);
                h[5] = fmaxf(areg[c*8+5] + b1v.y, 0.f);
                h[6] = fmaxf(areg[c*8+6] + b1v.z, 0.f);
                h[7] = fmaxf(areg[c*8+7] + b1v.w, 0.f);
                #pragma unroll
                for (int p2 = 0; p2 < 4; ++p2)
                    h1[c].u[p2] = cvt2(h[2*p2], h[2*p2+1]);
            }
            f32x4 acc[4];
            #pragma unroll
            for (int nt = 0; nt < 4; ++nt) {
                f32x4 z = {0.f, 0.f, 0.f, 0.f};
                z = __builtin_amdgcn_mfma_f32_16x16x32_bf16(h1[0].v, w2f[nt][0], z, 0, 0, 0);
                z = __builtin_amdgcn_mfma_f32_16x16x32_bf16(h1[1].v, w2f[nt][1], z, 0, 0, 0);
                acc[nt] = z;
            }
            float p[4];
            #pragma unroll
            for (int r = 0; r < 4; ++r) {
                float s = 0.f;
                #pragma unroll
                for (int nt = 0; nt < 4; ++nt)
                    s += fmaxf(acc[nt][r] + b2l[nt], 0.f) * w3l[nt];
                p[r] = s;
            }
            #pragma unroll
            for (int off = 1; off < 16; off <<= 1) {
                #pragma unroll
                for (int r = 0; r < 4; ++r)
                    p[r] += __shfl_xor(p[r], off, 64);
            }
            if (col < 4) {
                const int j = j0 + q*4 + col;
                float pv = p[0];
                pv = (col == 1) ? p[1] : pv;
                pv = (col == 2) ? p[2] : pv;
                pv = (col == 3) ? p[3] : pv;
                if (!((bm24[il*3 + (j >> 5)] >> (j & 31)) & 1u))
                    outr[j] = pv + b3v;
            }
        }
    }

    // ===== Phase D: fix (edge pairs), chunks of 16 keys per wave =====
    const int nk = *lcnt;
    const int k0 = q * 8;
    for (int ch = wave; ch*16 < nk; ch += 8) {
        union { bf16x8 v; unsigned u[4]; } h1[2];
        #pragma unroll
        for (int p2 = 0; p2 < 4; ++p2) { h1[0].u[p2] = 0; h1[1].u[p2] = 0; }

        const int s = ch*16 + col;
        if (s < nk) {
            const int fk   = fkeyL[s];
            const int key  = fk & 0xFFFF;
            const float cf = (float)(fk >> 16);
            const int ui = key / NPG, vi = key % NPG;

            float se[16];
            {
                const float4* p = (const float4*)(fseaG + ((size_t)blockIdx.x * EPG + s) * EF);
                #pragma unroll
                for (int q4 = 0; q4 < 4; ++q4) {
                    const float4 f = p[q4];
                    se[q4*4+0] = f.x; se[q4*4+1] = f.y;
                    se[q4*4+2] = f.z; se[q4*4+3] = f.w;
                }
            }

            float ck[16];
            #pragma unroll
            for (int kk = 0; kk < 8; ++kk) {
                ck[kk]     = cf * sbc[k0 + kk];
                ck[8 + kk] = cf * sbc[32 + k0 + kk];
            }
            #pragma unroll
            for (int qq = 0; qq < 16; ++qq) {
                const float sq = se[qq];
                const float4 w0  = *(const float4*)(sWEc + qq*64 + k0);
                const float4 w1  = *(const float4*)(sWEc + qq*64 + k0 + 4);
                const float4 w2v = *(const float4*)(sWEc + qq*64 + k0 + 32);
                const float4 w3v = *(const float4*)(sWEc + qq*64 + k0 + 36);
                ck[0]  += sq * w0.x;  ck[1]  += sq * w0.y;
                ck[2]  += sq * w0.z;  ck[3]  += sq * w0.w;
                ck[4]  += sq * w1.x;  ck[5]  += sq * w1.y;
                ck[6]  += sq * w1.z;  ck[7]  += sq * w1.w;
                ck[8]  += sq * w2v.x; ck[9]  += sq * w2v.y;
                ck[10] += sq * w2v.z; ck[11] += sq * w2v.w;
                ck[12] += sq * w3v.x; ck[13] += sq * w3v.y;
                ck[14] += sq * w3v.z; ck[15] += sq * w3v.w;
            }

            const float* Ar = sA + (ui - r0)*64;
            const float* Br = sB + vi*SBST;
            const float4 a0 = *(const float4*)(Ar + k0);
            const float4 a1 = *(const float4*)(Ar + k0 + 4);
            const float4 a2 = *(const float4*)(Ar + k0 + 32);
            const float4 a3 = *(const float4*)(Ar + k0 + 36);
            const float4 c0 = *(const float4*)(Br + k0);
            const float4 c1 = *(const float4*)(Br + k0 + 4);
            const float4 c2 = *(const float4*)(Br + k0 + 32);
            const float4 c3 = *(const float4*)(Br + k0 + 36);

            float h[16];
            h[0]  = fmaxf(a0.x + c0.x + ck[0],  0.f);
            h[1]  = fmaxf(a0.y + c0.y + ck[1],  0.f);
            h[2]  = fmaxf(a0.z + c0.z + ck[2],  0.f);
            h[3]  = fmaxf(a0.w + c0.w + ck[3],  0.f);
            h[4]  = fmaxf(a1.x + c1.x + ck[4],  0.f);
            h[5]  = fmaxf(a1.y + c1.y + ck[5],  0.f);
            h[6]  = fmaxf(a1.z + c1.z + ck[6],  0.f);
            h[7]  = fmaxf(a1.w + c1.w + ck[7],  0.f);
            h[8]  = fmaxf(a2.x + c2.x + ck[8],  0.f);
            h[9]  = fmaxf(a2.y + c2.y + ck[9],  0.f);
            h[10] = fmaxf(a2.z + c2.z + ck[10], 0.f);
            h[11] = fmaxf(a2.w + c2.w + ck[11], 0.f);
            h[12] = fmaxf(a3.x + c3.x + ck[12], 0.f);
            h[13] = fmaxf(a3.y + c3.y + ck[13], 0.f);
            h[14] = fmaxf(a3.z + c3.z + ck[14], 0.f);
            h[15] = fmaxf(a3.w + c3.w + ck[15], 0.f);
            #pragma unroll
            for (int p2 = 0; p2 < 4; ++p2) {
                h1[0].u[p2] = cvt2(h[2*p2],     h[2*p2 + 1]);
                h1[1].u[p2] = cvt2(h[8 + 2*p2], h[8 + 2*p2 + 1]);
            }
        }

        f32x4 acc[4];
        #pragma unroll
        for (int nt = 0; nt < 4; ++nt) {
            f32x4 z = {0.f, 0.f, 0.f, 0.f};
            z = __builtin_amdgcn_mfma_f32_16x16x32_bf16(h1[0].v, w2f[nt][0], z, 0, 0, 0);
            z = __builtin_amdgcn_mfma_f32_16x16x32_bf16(h1[1].v, w2f[nt][1], z, 0, 0, 0);
            acc[nt] = z;
        }

        float p[4];
        #pragma unroll
        for (int r = 0; r < 4; ++r) {
            float sum = 0.f;
            #pragma unroll
            for (int nt = 0; nt < 4; ++nt)
                sum += fmaxf(acc[nt][r] + b2l[nt], 0.f) * w3l[nt];
            p[r] = sum;
        }
        #pragma unroll
        for (int off = 1; off < 16; off <<= 1) {
            #pragma unroll
            for (int r = 0; r < 4; ++r)
                p[r] += __shfl_xor(p[r], off, 64);
        }
        if (col < 4) {
            const int lr = q*4 + col;
            if (ch*16 + lr < nk) {
                float pv = p[0];
                pv = (col == 1) ? p[1] : pv;
                pv = (col == 2) ? p[2] : pv;
                pv = (col == 3) ? p[3] : pv;
                out[g*PPG + (fkeyL[ch*16 + lr] & 0xFFFF)] = pv + b3v;
            }
        }
    }
}

// ---------------------------------------------------------------------------
extern "C" void kernel_launch(void* const* d_in, const int* in_sizes, int n_in,
                              void* d_out, int out_size, void* d_ws, size_t ws_size,
                              hipStream_t stream)
{
    const float* x      = (const float*)d_in[0];
    const float* ea     = (const float*)d_in[1];
    const int*   eidx   = (const int*)  d_in[2];
    // d_in[3]=idx0, d_in[4]=idx1, d_in[5]=n  -- derivable, unused
    const float* W_atom = (const float*)d_in[6];
    const float* b_atom = (const float*)d_in[7];
    const float* W_bond = (const float*)d_in[8];
    const float* b_bond = (const float*)d_in[9];
    const float* W_node = (const float*)d_in[10];
    const float* b_node = (const float*)d_in[11];
    const float* W_edge = (const float*)d_in[12];
    const float* b_edge = (const float*)d_in[13];
    const float* W1     = (const float*)d_in[14];
    const float* b1     = (const float*)d_in[15];
    const float* W2     = (const float*)d_in[16];
    const float* b2     = (const float*)d_in[17];
    const float* W3     = (const float*)d_in[18];
    const float* b3     = (const float*)d_in[19];
    float* out = (float*)d_out;

    // Workspace: only the per-block fsea slices (256 blocks x 768 x 16 f32)
    float* fseaG = (float*)d_ws;

    fused_kernel<<<BGR*4, 512, 0, stream>>>(
        x, W_atom, b_atom, W_node, b_node, W1, b1,
        ea, eidx, W_bond, b_bond, W_edge, b_edge,
        W2, b2, W3, b3, fseaG, out);
}

// Round 5
// 137.138 us; speedup vs baseline: 1.6745x; 1.6745x over previous
//
#include <hip/hip_runtime.h>
#if __has_include(<hip/hip_bf16.h>)
#include <hip/hip_bf16.h>
#define HAVE_BF16_H 1
#endif

// Problem constants (fixed by harness)
#define NPG 96                  // nodes per graph
#define BGR 64                  // graphs
#define HID 64
#define INF 32
#define EF  16
#define DEG 8
#define NN  (BGR*NPG)           // 6144 nodes
#define NE  (BGR*NPG*DEG)       // 49152 edges
#define EPG (NPG*DEG)           // 768 edges per graph
#define PPG (NPG*NPG)           // 9216 pairs per graph
#define BMW 288                 // bitmap words per graph (9216 bits)

typedef short bf16x8 __attribute__((ext_vector_type(8)));
typedef float f32x4  __attribute__((ext_vector_type(4)));

__device__ __forceinline__ unsigned rne2(float lo, float hi) {
    union { float f; unsigned u; } a, b; a.f = lo; b.f = hi;
    unsigned ua = a.u + 0x7FFF + ((a.u >> 16) & 1);
    unsigned ub = b.u + 0x7FFF + ((b.u >> 16) & 1);
    return (ua >> 16) | (ub & 0xFFFF0000u);
}
__device__ __forceinline__ unsigned short rne1(float x) {
    union { float f; unsigned u; } a; a.f = x;
    return (unsigned short)((a.u + 0x7FFF + ((a.u >> 16) & 1)) >> 16);
}
// Pack 2 floats -> 2 bf16 (RNE); lowers to v_cvt_pk_bf16_f32 on gfx950.
__device__ __forceinline__ unsigned cvt2(float lo, float hi) {
#ifdef HAVE_BF16_H
    __hip_bfloat162 h2 = __float22bfloat162_rn(make_float2(lo, hi));
    unsigned u; __builtin_memcpy(&u, &h2, 4); return u;
#else
    return rne2(lo, hi);
#endif
}

// ---------------------------------------------------------------------------
// K1 "prep": blocks 0..63 = per-graph edge dedup (+ edge bitmap; block 0 also
// folds WEc/biasc and pre-converts W2^T to padded bf16 in ws). Blocks
// 64..575 = node chain, 12 nodes/block (1/wave).
// ---------------------------------------------------------------------------
__global__ __launch_bounds__(768) void prep_kernel(
    const float* __restrict__ x,
    const float* __restrict__ W_atom, const float* __restrict__ b_atom,
    const float* __restrict__ W_node, const float* __restrict__ b_node,
    const float* __restrict__ W1,     const float* __restrict__ b1,
    const float* __restrict__ ea,     const int* __restrict__ eidx,
    const float* __restrict__ W_bond, const float* __restrict__ b_bond,
    const float* __restrict__ W_edge, const float* __restrict__ b_edge,
    const float* __restrict__ W2,
    float* __restrict__ Abuf, float* __restrict__ Bbuf,
    int* __restrict__ fkey, int* __restrict__ fcnt,
    float* __restrict__ fsea, int* __restrict__ gcount,
    float* __restrict__ wec, float* __restrict__ biascg,
    unsigned* __restrict__ gbm, unsigned short* __restrict__ w2bf)
{
    __shared__ __align__(16) char smem[45504];
    const int t = threadIdx.x;

    if (blockIdx.x >= 64) {
        // ---------------- node path: 12 nodes per block ----------------
        float* sh = (float*)smem;               // [12][64]
        const int wave = t >> 6, lane = t & 63;
        const int n = __builtin_amdgcn_readfirstlane((blockIdx.x - 64)*12 + wave);
        const float* xr = x + n * INF;

        float xh = b_atom[lane];
        #pragma unroll
        for (int k = 0; k < INF; ++k) xh += xr[k] * W_atom[k*HID + lane];
        sh[wave*64 + lane] = xh;
        __syncthreads();

        float en = b_node[lane];
        #pragma unroll
        for (int k = 0; k < HID; ++k) en += sh[wave*64 + k] * W_node[k*HID + lane];
        __syncthreads();
        sh[wave*64 + lane] = en;
        __syncthreads();

        float a = b1[lane], b = 0.f;
        #pragma unroll
        for (int k = 0; k < HID; ++k) {
            const float ek = sh[wave*64 + k];
            a += ek * W1[k*HID + lane];
            b += ek * W1[(HID + k)*HID + lane];
        }
        Abuf[n*HID + lane] = a;
        Bbuf[n*HID + lane] = b;
        return;
    }

    // ---------------- dedup path: one graph per block ----------------
    int*      head = (int*)smem;                          // 36864
    int*      nxt  = (int*)(smem + 36864);                //  3072
    float*    sU   = (float*)(smem + 36864 + 3072);       //  4096
    float*    sbe  = (float*)(smem + 36864 + 3072 + 4096);//   256
    unsigned* bm   = (unsigned*)(smem + 36864+3072+4096+256); // 1152
    int*      lcnt = (int*)(smem + 36864+3072+4096+256+1152);
    const int g = blockIdx.x;

    for (int idx = t; idx < PPG; idx += EPG) head[idx] = -1;
    for (int idx = t; idx < BMW; idx += EPG) bm[idx] = 0u;
    if (t == 0) *lcnt = 0;

    const int u = eidx[g*EPG + t]      - g*NPG;
    const int v = eidx[NE + g*EPG + t] - g*NPG;
    const int key = u*NPG + v;
    __syncthreads();

    nxt[t] = atomicExch(&head[key], t);
    __syncthreads();

    if (head[key] == t) {
        const float* eag = ea + (size_t)g * EPG * EF;
        float s[EF];
        #pragma unroll
        for (int q = 0; q < EF; ++q) s[q] = 0.f;
        int cnt = 0;
        for (int e = t; e != -1; e = nxt[e]) {
            ++cnt;
            const float4* p = (const float4*)(eag + e*EF);
            #pragma unroll
            for (int q4 = 0; q4 < 4; ++q4) {
                const float4 f = p[q4];
                s[q4*4+0] += f.x; s[q4*4+1] += f.y;
                s[q4*4+2] += f.z; s[q4*4+3] += f.w;
            }
        }
        atomicOr(&bm[key >> 5], 1u << (key & 31));
        const int pos  = atomicAdd(lcnt, 1);
        const int slot = g*EPG + pos;
        fkey[slot] = key;
        fcnt[slot] = cnt;
        #pragma unroll
        for (int q = 0; q < EF; ++q) fsea[slot*EF + q] = s[q];
    }
    __syncthreads();
    for (int idx = t; idx < BMW; idx += EPG) gbm[g*BMW + idx] = bm[idx];
    if (t == 0) gcount[g] = *lcnt;

    // ---- block 0: fold WEc = W_bond@W_edge@W1c, biasc; W2^T -> bf16 ----
    if (g == 0) {
        // padded bf16 W2^T: w2bf[n*72 + k] = bf16(W2[k][n]); pad cols zeroed
        for (int idx = t; idx < 64*64; idx += EPG) {
            const int k = idx >> 6, n = idx & 63;
            w2bf[n*72 + k] = rne1(W2[idx]);
        }
        for (int idx = t; idx < 64*8; idx += EPG) {
            const int n = idx >> 3, kk = 64 + (idx & 7);
            w2bf[n*72 + kk] = 0;
        }
        for (int idx = t; idx < 16*64; idx += EPG) {
            const int r = idx >> 6, c = idx & 63;
            float s = 0.f;
            for (int k = 0; k < 64; ++k) s += W_bond[r*64+k] * W_edge[k*64+c];
            sU[idx] = s;
        }
        if (t < 64) {
            float s2 = b_edge[t];
            for (int k = 0; k < 64; ++k) s2 += b_bond[k] * W_edge[k*64+t];
            sbe[t] = s2;
        }
        __syncthreads();
        for (int idx = t; idx < 16*64; idx += EPG) {
            const int r = idx >> 6, c = idx & 63;
            float s = 0.f;
            for (int k = 0; k < 64; ++k) s += sU[r*64+k] * W1[(128+k)*64+c];
            wec[idx] = s;
        }
        if (t < 64) {
            float sc = 0.f;
            for (int k = 0; k < 64; ++k) sc += sbe[k] * W1[(128+k)*64+t];
            biascg[t] = sc;
        }
    }
}

// ---------------------------------------------------------------------------
// K2 "pair": blocks 0..767 = dense MFMA pair MLP, but SKIP stores for pairs
// with >=1 edge (bitmap-predicated stores). Blocks 768..1535 = MFMA edge-pair
// MLP with sparse term; writes exactly the masked keys. Write sets are
// disjoint, so both halves run concurrently in one dispatch.
// W2^T bf16 fragments are read DIRECTLY from global w2bf (L2-hot, identical
// bits) -- no LDS staging pass; dense LDS 37.5K -> 28.3K (5 blocks/CU cap).
// ---------------------------------------------------------------------------
#define SBST 68                 // sB row stride (floats); 68*4=272 keeps 16B align
#define W2ST 72                 // w2bf row stride (ushorts); 72*2=144 keeps 16B align
#define FIXW 16                 // slots per wave (fix half)
__global__ __launch_bounds__(256) void pair_kernel(
    const float* __restrict__ Abuf, const float* __restrict__ Bbuf,
    const int* __restrict__ fkey, const int* __restrict__ fcnt,
    const float* __restrict__ fsea, const int* __restrict__ gcount,
    const float* __restrict__ wec,  const float* __restrict__ biascg,
    const unsigned* __restrict__ gbm, const unsigned short* __restrict__ w2bf,
    const float* __restrict__ b2,
    const float* __restrict__ W3,   const float* __restrict__ b3,
    float* __restrict__ out)
{
    __shared__ __align__(16) char smem[28288];
    const int t = threadIdx.x;
    const int wave = t >> 6, lane = t & 63;
    const int col = lane & 15, q = lane >> 4;
    const float b3v = b3[0];

    if (blockIdx.x < 768) {
        // ================= dense half =================
        float*    sB  = (float*)smem;                    // 26112
        float*    sA  = (float*)(smem + 26112);          //  2048
        unsigned* sBM = (unsigned*)(smem + 28160);       //    96
        const int g  = blockIdx.x / 12;
        const int i0 = (blockIdx.x % 12) * 8;

        // sB: 96 rows x 64 floats, float4 loads + padded b128 stores (6 iter)
        {
            const float4* Bg4 = (const float4*)(Bbuf + g * NPG * 64);
            #pragma unroll
            for (int it = 0; it < 6; ++it) {
                const int idx4 = t + it*256;           // 0..1535
                const int row = idx4 >> 4, c4 = idx4 & 15;
                *(float4*)(sB + row*SBST + c4*4) = Bg4[idx4];
            }
        }
        // sA: 8 rows x 64 floats = 128 float4 (contiguous)
        if (t < 128)
            ((float4*)sA)[t] = ((const float4*)(Abuf + (g*NPG + i0)*64))[t];
        if (t < 24) sBM[t] = gbm[g*BMW + i0*3 + t];

        // w2f fragments straight from global (L2-hot; 16B-aligned)
        bf16x8 w2f[4][2];
        #pragma unroll
        for (int nt = 0; nt < 4; ++nt)
            #pragma unroll
            for (int c = 0; c < 2; ++c)
                w2f[nt][c] = *(const bf16x8*)(w2bf + (nt*16 + col)*W2ST + c*32 + q*8);

        float w3l[4], b2l[4];
        #pragma unroll
        for (int nt = 0; nt < 4; ++nt) {
            w3l[nt] = W3[nt*16 + col];
            b2l[nt] = b2[nt*16 + col];
        }
        __syncthreads();

        #pragma unroll
        for (int ii = 0; ii < 2; ++ii) {
            const int il = wave*2 + ii;
            float areg[16];
            {
                const float4* Ar = (const float4*)(sA + il*64 + q*8);
                const float4 a0 = Ar[0], a1 = Ar[1];
                const float4 a2 = Ar[8], a3 = Ar[9];
                areg[0]=a0.x; areg[1]=a0.y; areg[2]=a0.z; areg[3]=a0.w;
                areg[4]=a1.x; areg[5]=a1.y; areg[6]=a1.z; areg[7]=a1.w;
                areg[8]=a2.x; areg[9]=a2.y; areg[10]=a2.z; areg[11]=a2.w;
                areg[12]=a3.x; areg[13]=a3.y; areg[14]=a3.z; areg[15]=a3.w;
            }
            float* outr = out + g*PPG + (i0 + il)*NPG;

            for (int jc = 0; jc < 6; ++jc) {
                const int j0 = jc * 16;
                union { bf16x8 v; unsigned u[4]; } h1[2];
                const float* Brow = sB + (j0 + col)*SBST + q*8;
                #pragma unroll
                for (int c = 0; c < 2; ++c) {
                    const float4 b0 = *(const float4*)(Brow + c*32);
                    const float4 b1v = *(const float4*)(Brow + c*32 + 4);
                    float h[8];
                    h[0] = fmaxf(areg[c*8+0] + b0.x, 0.f);
                    h[1] = fmaxf(areg[c*8+1] + b0.y, 0.f);
                    h[2] = fmaxf(areg[c*8+2] + b0.z, 0.f);
                    h[3] = fmaxf(areg[c*8+3] + b0.w, 0.f);
                    h[4] = fmaxf(areg[c*8+4] + b1v.x, 0.f);
                    h[5] = fmaxf(areg[c*8+5] + b1v.y, 0.f);
                    h[6] = fmaxf(areg[c*8+6] + b1v.z, 0.f);
                    h[7] = fmaxf(areg[c*8+7] + b1v.w, 0.f);
                    #pragma unroll
                    for (int p2 = 0; p2 < 4; ++p2)
                        h1[c].u[p2] = cvt2(h[2*p2], h[2*p2+1]);
                }
                f32x4 acc[4];
                #pragma unroll
                for (int nt = 0; nt < 4; ++nt) {
                    f32x4 z = {0.f, 0.f, 0.f, 0.f};
                    z = __builtin_amdgcn_mfma_f32_16x16x32_bf16(h1[0].v, w2f[nt][0], z, 0, 0, 0);
                    z = __builtin_amdgcn_mfma_f32_16x16x32_bf16(h1[1].v, w2f[nt][1], z, 0, 0, 0);
                    acc[nt] = z;
                }
                float p[4];
                #pragma unroll
                for (int r = 0; r < 4; ++r) {
                    float s = 0.f;
                    #pragma unroll
                    for (int nt = 0; nt < 4; ++nt)
                        s += fmaxf(acc[nt][r] + b2l[nt], 0.f) * w3l[nt];
                    p[r] = s;
                }
                #pragma unroll
                for (int off = 1; off < 16; off <<= 1) {
                    #pragma unroll
                    for (int r = 0; r < 4; ++r)
                        p[r] += __shfl_xor(p[r], off, 64);
                }
                // After the butterfly every lane holds p[0..3]; 16 lanes
                // (col<4 of each q-group) emit one contiguous 64B segment.
                if (col < 4) {
                    const int j = j0 + q*4 + col;
                    float pv = p[0];
                    pv = (col == 1) ? p[1] : pv;
                    pv = (col == 2) ? p[2] : pv;
                    pv = (col == 3) ? p[3] : pv;
                    if (!((sBM[il*3 + (j >> 5)] >> (j & 31)) & 1u))
                        outr[j] = pv + b3v;
                }
            }
        }
        return;
    }

    // ================= fix half (edge pairs) =================
    float* sWEc = (float*)smem;            // 4096
    float* sbc  = (float*)(smem + 4096);   //  256

    for (int idx = t; idx < 16*64; idx += 256) sWEc[idx] = wec[idx];
    if (t < 64) sbc[t] = biascg[t];
    __syncthreads();

    const int fb = blockIdx.x - 768;
    const int s0 = (fb * 4 + wave) * FIXW;
    const int g  = s0 / EPG;
    const int l0 = s0 % EPG;
    const int cg = gcount[g];
    if (l0 >= cg) return;

    bf16x8 w2f[4][2];
    #pragma unroll
    for (int nt = 0; nt < 4; ++nt)
        #pragma unroll
        for (int c = 0; c < 2; ++c)
            w2f[nt][c] = *(const bf16x8*)(w2bf + (nt*16 + col)*W2ST + c*32 + q*8);

    float w3l[4], b2l[4];
    #pragma unroll
    for (int nt = 0; nt < 4; ++nt) {
        w3l[nt] = W3[nt*16 + col];
        b2l[nt] = b2[nt*16 + col];
    }
    const int k0 = q * 8;

    union { bf16x8 v; unsigned u[4]; } h1[2];
    #pragma unroll
    for (int p2 = 0; p2 < 4; ++p2) { h1[0].u[p2] = 0; h1[1].u[p2] = 0; }

    const int s = s0 + col;
    if (l0 + col < cg) {
        const int key  = fkey[s];
        const float cf = (float)fcnt[s];
        const int ui = key / NPG, vi = key % NPG;

        float se[16];
        {
            const float4* p = (const float4*)(fsea + (size_t)s * EF);
            #pragma unroll
            for (int q4 = 0; q4 < 4; ++q4) {
                const float4 f = p[q4];
                se[q4*4+0] = f.x; se[q4*4+1] = f.y;
                se[q4*4+2] = f.z; se[q4*4+3] = f.w;
            }
        }

        float ck[16];
        #pragma unroll
        for (int kk = 0; kk < 8; ++kk) {
            ck[kk]     = cf * sbc[k0 + kk];
            ck[8 + kk] = cf * sbc[32 + k0 + kk];
        }
        #pragma unroll
        for (int qq = 0; qq < 16; ++qq) {
            const float sq = se[qq];
            const float4 w0 = *(const float4*)(sWEc + qq*64 + k0);
            const float4 w1 = *(const float4*)(sWEc + qq*64 + k0 + 4);
            const float4 w2v = *(const float4*)(sWEc + qq*64 + k0 + 32);
            const float4 w3v = *(const float4*)(sWEc + qq*64 + k0 + 36);
            ck[0]  += sq * w0.x;  ck[1]  += sq * w0.y;
            ck[2]  += sq * w0.z;  ck[3]  += sq * w0.w;
            ck[4]  += sq * w1.x;  ck[5]  += sq * w1.y;
            ck[6]  += sq * w1.z;  ck[7]  += sq * w1.w;
            ck[8]  += sq * w2v.x; ck[9]  += sq * w2v.y;
            ck[10] += sq * w2v.z; ck[11] += sq * w2v.w;
            ck[12] += sq * w3v.x; ck[13] += sq * w3v.y;
            ck[14] += sq * w3v.z; ck[15] += sq * w3v.w;
        }

        const float* Ar = Abuf + (g*NPG + ui)*64;
        const float* Br = Bbuf + (g*NPG + vi)*64;
        const float4 a0 = *(const float4*)(Ar + k0);
        const float4 a1 = *(const float4*)(Ar + k0 + 4);
        const float4 a2 = *(const float4*)(Ar + k0 + 32);
        const float4 a3 = *(const float4*)(Ar + k0 + 36);
        const float4 c0 = *(const float4*)(Br + k0);
        const float4 c1 = *(const float4*)(Br + k0 + 4);
        const float4 c2 = *(const float4*)(Br + k0 + 32);
        const float4 c3 = *(const float4*)(Br + k0 + 36);

        float h[16];
        h[0]  = fmaxf(a0.x + c0.x + ck[0],  0.f);
        h[1]  = fmaxf(a0.y + c0.y + ck[1],  0.f);
        h[2]  = fmaxf(a0.z + c0.z + ck[2],  0.f);
        h[3]  = fmaxf(a0.w + c0.w + ck[3],  0.f);
        h[4]  = fmaxf(a1.x + c1.x + ck[4],  0.f);
        h[5]  = fmaxf(a1.y + c1.y + ck[5],  0.f);
        h[6]  = fmaxf(a1.z + c1.z + ck[6],  0.f);
        h[7]  = fmaxf(a1.w + c1.w + ck[7],  0.f);
        h[8]  = fmaxf(a2.x + c2.x + ck[8],  0.f);
        h[9]  = fmaxf(a2.y + c2.y + ck[9],  0.f);
        h[10] = fmaxf(a2.z + c2.z + ck[10], 0.f);
        h[11] = fmaxf(a2.w + c2.w + ck[11], 0.f);
        h[12] = fmaxf(a3.x + c3.x + ck[12], 0.f);
        h[13] = fmaxf(a3.y + c3.y + ck[13], 0.f);
        h[14] = fmaxf(a3.z + c3.z + ck[14], 0.f);
        h[15] = fmaxf(a3.w + c3.w + ck[15], 0.f);
        #pragma unroll
        for (int p2 = 0; p2 < 4; ++p2) {
            h1[0].u[p2] = cvt2(h[2*p2],     h[2*p2 + 1]);
            h1[1].u[p2] = cvt2(h[8 + 2*p2], h[8 + 2*p2 + 1]);
        }
    }

    f32x4 acc[4];
    #pragma unroll
    for (int nt = 0; nt < 4; ++nt) {
        f32x4 z = {0.f, 0.f, 0.f, 0.f};
        z = __builtin_amdgcn_mfma_f32_16x16x32_bf16(h1[0].v, w2f[nt][0], z, 0, 0, 0);
        z = __builtin_amdgcn_mfma_f32_16x16x32_bf16(h1[1].v, w2f[nt][1], z, 0, 0, 0);
        acc[nt] = z;
    }

    float p[4];
    #pragma unroll
    for (int r = 0; r < 4; ++r) {
        float sum = 0.f;
        #pragma unroll
        for (int nt = 0; nt < 4; ++nt)
            sum += fmaxf(acc[nt][r] + b2l[nt], 0.f) * w3l[nt];
        p[r] = sum;
    }
    #pragma unroll
    for (int off = 1; off < 16; off <<= 1) {
        #pragma unroll
        for (int r = 0; r < 4; ++r)
            p[r] += __shfl_xor(p[r], off, 64);
    }
    if (col < 4) {
        const int lr = q*4 + col;
        if (l0 + lr < cg) {
            float pv = p[0];
            pv = (col == 1) ? p[1] : pv;
            pv = (col == 2) ? p[2] : pv;
            pv = (col == 3) ? p[3] : pv;
            out[g*PPG + fkey[s0 + lr]] = pv + b3v;
        }
    }
}

// ---------------------------------------------------------------------------
extern "C" void kernel_launch(void* const* d_in, const int* in_sizes, int n_in,
                              void* d_out, int out_size, void* d_ws, size_t ws_size,
                              hipStream_t stream)
{
    const float* x      = (const float*)d_in[0];
    const float* ea     = (const float*)d_in[1];
    const int*   eidx   = (const int*)  d_in[2];
    // d_in[3]=idx0, d_in[4]=idx1, d_in[5]=n  -- derivable, unused
    const float* W_atom = (const float*)d_in[6];
    const float* b_atom = (const float*)d_in[7];
    const float* W_bond = (const float*)d_in[8];
    const float* b_bond = (const float*)d_in[9];
    const float* W_node = (const float*)d_in[10];
    const float* b_node = (const float*)d_in[11];
    const float* W_edge = (const float*)d_in[12];
    const float* b_edge = (const float*)d_in[13];
    const float* W1     = (const float*)d_in[14];
    const float* b1     = (const float*)d_in[15];
    const float* W2     = (const float*)d_in[16];
    const float* b2     = (const float*)d_in[17];
    const float* W3     = (const float*)d_in[18];
    const float* b3     = (const float*)d_in[19];
    float* out = (float*)d_out;

    float* ws    = (float*)d_ws;
    float* Abuf  = ws;                       // [NN,64]
    float* Bbuf  = Abuf  + NN*HID;           // [NN,64]
    float* fsea  = Bbuf  + NN*HID;           // [NE,16]
    int*   fkey  = (int*)(fsea + NE*EF);     // [NE]
    int*   fcnt  = fkey + NE;                // [NE]
    int*   gcount= fcnt + NE;                // [BGR]
    float* wec   = (float*)(gcount + BGR);   // [16,64]
    float* biascg= wec + 16*64;              // [64]
    unsigned* gbm= (unsigned*)(biascg + 64); // [BGR,288]
    unsigned short* w2bf = (unsigned short*)(gbm + BGR*BMW); // [64,72] bf16 (16B-aligned)

    prep_kernel<<<64 + NN/12, 768, 0, stream>>>(
        x, W_atom, b_atom, W_node, b_node, W1, b1,
        ea, eidx, W_bond, b_bond, W_edge, b_edge, W2,
        Abuf, Bbuf, fkey, fcnt, fsea, gcount, wec, biascg, gbm, w2bf);
    pair_kernel<<<768 + NE/(FIXW*4), 256, 0, stream>>>(
        Abuf, Bbuf, fkey, fcnt, fsea, gcount, wec, biascg, gbm, w2bf,
        b2, W3, b3, out);
}